// Round 6
// baseline (12246.651 us; speedup 1.0000x reference)
//
#include <hip/hip_runtime.h>
#include <math.h>

#define VIS 1024
#define HID 1024
#define NROW 8192
#define KDIM 2048
#define NDIM 2048
#define NSTEPS 2010
#define KLS 10

__global__ __launch_bounds__(256) void init_zero(float* p, int n) {
    int i = blockIdx.x * 256 + threadIdx.x;
    if (i < n) p[i] = 0.f;
}

__global__ __launch_bounds__(256) void transpose_w_k(const float* __restrict__ w,
                                                     float* __restrict__ wT) {
    __shared__ float tile[32][33];
    int bx = blockIdx.x * 32, by = blockIdx.y * 32;
    int tx = threadIdx.x & 31, ty = threadIdx.x >> 5;  // ty 0..7
    #pragma unroll
    for (int m = 0; m < 4; ++m) {
        int y = by + ty + m * 8;
        tile[ty + m * 8][tx] = w[(size_t)y * 1024 + bx + tx];
    }
    __syncthreads();
    #pragma unroll
    for (int m = 0; m < 4; ++m) {
        int y = bx + ty + m * 8;
        wT[(size_t)y * 1024 + by + tx] = tile[tx][ty + m * 8];
    }
}

// precompute decision thresholds: thr = log(u) - log1p(-u) - bias  (f64, offloaded
// to the full chip so the serial gibbs CU never runs a f64 log)
__global__ __launch_bounds__(256) void prep_thr(
    const float* __restrict__ u_h, const float* __restrict__ u_v,
    const float* __restrict__ bh, const float* __restrict__ bv,
    double* __restrict__ thrH, double* __restrict__ thrV)
{
    int i = blockIdx.x * 256 + threadIdx.x;
    if (i < NSTEPS * 1024) {
        int jj = i & 1023;
        double uh = (double)u_h[i];
        thrH[i] = log(uh) - log1p(-uh) - (double)bh[jj];
        double uv = (double)u_v[i];
        thrV[i] = log(uv) - log1p(-uv) - (double)bv[jj];
    }
}

// ---------------- shared-memory union for the fused kernel ----------------
struct SGibbs {
    int wcnt[16] __attribute__((aligned(16)));   // per-wave flip counts
    int sidx[1088] __attribute__((aligned(16))); // flip list: (row<<12)|(valid<<1)|bit
    double redd[16];
};
struct SMm1 {
    float As[8][136];
    float Bs[8][136];
    float red[128 * 33];
};
union SharedU { SGibbs g; SMm1 m; };

// build padded flip list; every thread returns npad (multiple of 32).
__device__ __forceinline__ int build_list(SGibbs& sg, bool flip, int entry,
                                          int wv, int lane, int tid) {
    unsigned long long fm = __ballot(flip);
    int myrank = __popcll(fm & ((1ull << lane) - 1ull));
    if (lane == 0) sg.wcnt[wv] = __popcll(fm);
    __syncthreads();                               // B1: counts (and prev reads done)
    const int4* wc = (const int4*)sg.wcnt;
    int4 c0 = wc[0], c1 = wc[1], c2 = wc[2], c3 = wc[3];
    int cs[16] = {c0.x, c0.y, c0.z, c0.w, c1.x, c1.y, c1.z, c1.w,
                  c2.x, c2.y, c2.z, c2.w, c3.x, c3.y, c3.z, c3.w};
    int off = 0, n = 0;
    #pragma unroll
    for (int u = 0; u < 16; ++u) { if (u < wv) off += cs[u]; n += cs[u]; }
    if (flip) sg.sidx[off + myrank] = entry;
    int npad = (n + 31) & ~31;
    if (tid < npad - n) sg.sidx[n + tid] = 0;      // invalid pad: contributes 0
    __syncthreads();                               // B2: list ready
    return npad;
}

// 32-wide flat apply: 32 independent loads in flight -> one latency window.
__device__ __forceinline__ void apply32(double& acc, const SGibbs& sg, int npad,
                                        const char* Mjb) {
    for (int i = 0; i < npad; i += 32) {
        const int4* sp = (const int4*)&sg.sidx[i];
        int e[32];
        #pragma unroll
        for (int q = 0; q < 8; ++q) {
            int4 t4 = sp[q];
            e[4 * q] = t4.x; e[4 * q + 1] = t4.y; e[4 * q + 2] = t4.z; e[4 * q + 3] = t4.w;
        }
        float v[32];
        #pragma unroll
        for (int q = 0; q < 32; ++q)
            v[q] = *(const float*)(Mjb + (e[q] & 0x3FF000));
        #pragma unroll
        for (int q = 0; q < 32; ++q) {
            double d = (e[q] & 1) ? (double)v[q] : -(double)v[q];
            acc += (e[q] & 2) ? d : 0.0;
        }
    }
}

// ---- fused: block 0 = whole Gibbs chain (1 WG, flip-incremental, f64);
// ----        blocks 1..1024 = GEMM1 + zeta + log-posterior epilogue.
__global__ __launch_bounds__(1024) void fused_k(
    const float* __restrict__ w, const float* __restrict__ wT,
    const float* __restrict__ bv, const float* __restrict__ bh,
    const float* __restrict__ u_init, const float* __restrict__ u_h,
    const float* __restrict__ u_v, double* __restrict__ fes,
    const double* __restrict__ thrHp, const double* __restrict__ thrVp, int use_pre,
    const float* __restrict__ A, const float* __restrict__ B,
    const float* __restrict__ lb, const float* __restrict__ eps,
    float* __restrict__ zv, float* __restrict__ zh, float* __restrict__ lp_row)
{
    __shared__ SharedU su;
    const int tid = threadIdx.x;

    if (blockIdx.x == 0) {
        // ======================= GIBBS (single WG) =======================
        SGibbs& sg = su.g;
        const int j = tid;                 // column 0..1023
        const int wv = tid >> 6, lane = tid & 63;
        const double bhj = (double)bh[j], bvj = (double)bv[j];
        const char* wjb  = (const char*)w  + (size_t)j * 4;
        const char* wTjb = (const char*)wT + (size_t)j * 4;
        double doth = 0.0, dotv = 0.0, fe_acc = 0.0;

        bool mybit_v = (u_init[j] >= 0.5f);
        bool mybit_h = false;
        // initial doth = sv0 @ w (flips vs virtual all-zero state)
        double thrH;
        if (use_pre) thrH = thrHp[j];
        else { double u = (double)u_h[j]; thrH = log(u) - log1p(-u) - bhj; }
        {
            int np0 = build_list(sg, mybit_v, (j << 12) | 3, wv, lane, tid);
            apply32(doth, sg, np0, wjb);
        }

        for (int t = 0; t < NSTEPS; ++t) {
            // ---- phase a: sh_j = (doth <= thrH) ----
            bool nh = (doth <= thrH);
            bool flipH = (nh != mybit_h); mybit_h = nh;
            double thrV;
            if (use_pre) thrV = thrVp[(size_t)t * 1024 + j];
            else { double u = (double)u_v[(size_t)t * 1024 + j]; thrV = log(u) - log1p(-u) - bvj; }
            int np = build_list(sg, flipH, (j << 12) | 2 | (nh ? 1 : 0), wv, lane, tid);
            apply32(dotv, sg, np, wTjb);          // dotv tracks sh @ wT

            // ---- phase b: sv2_j = (dotv <= thrV) ----
            bool nv = (dotv <= thrV);
            bool flipV = (nv != mybit_v); mybit_v = nv;
            if (t + 1 < NSTEPS) {
                if (use_pre) thrH = thrHp[(size_t)(t + 1) * 1024 + j];
                else { double u = (double)u_h[(size_t)(t + 1) * 1024 + j]; thrH = log(u) - log1p(-u) - bhj; }
            }
            np = build_list(sg, flipV, (j << 12) | 2 | (nv ? 1 : 0), wv, lane, tid);
            apply32(doth, sg, np, wjb);           // doth tracks sv2 @ w

            // ---- sample free energy: fe = sv2.bv + sh.(bh + doth) ----
            if (t >= NSTEPS - KLS) {
                double c = (nv ? bvj : 0.0) + (nh ? (bhj + doth) : 0.0);
                #pragma unroll
                for (int o = 32; o > 0; o >>= 1) c += __shfl_down(c, o);
                if (lane == 0) sg.redd[wv] = c;
                __syncthreads();
                if (tid == 0) {
                    double s2 = 0.0;
                    for (int q = 0; q < 16; ++q) s2 += sg.redd[q];
                    fe_acc += s2;
                }
                __syncthreads();
            }
        }
        if (tid == 0) fes[0] = fe_acc;
        return;
    }

    // ======================= GEMM1 (+ zeta + log-posterior) =======================
    const int gid = blockIdx.x - 1;
    const int n0 = (gid & 15) * 128;
    const int m0 = (gid >> 4) * 128;
    const int tx = tid & 31, ty = tid >> 5;       // 32x32 grid of 4x4 microtiles
    const int lr = tid >> 3, lk = tid & 7;        // A-tile load coords
    const int br2 = tid >> 7, bc2 = tid & 127;    // B-tile load coords

    float acc[4][4];
    #pragma unroll
    for (int i = 0; i < 4; ++i)
        #pragma unroll
        for (int jj = 0; jj < 4; ++jj) acc[i][jj] = 0.f;

    float a_reg = A[(size_t)(m0 + lr) * KDIM + lk];
    float b_reg = B[(size_t)br2 * NDIM + n0 + bc2];
    for (int k0 = 0; k0 < KDIM; k0 += 8) {
        __syncthreads();
        su.m.As[lk][lr] = a_reg;
        su.m.Bs[br2][bc2] = b_reg;
        __syncthreads();
        if (k0 + 8 < KDIM) {                        // register prefetch of next tile
            a_reg = A[(size_t)(m0 + lr) * KDIM + (k0 + 8) + lk];
            b_reg = B[(size_t)(k0 + 8 + br2) * NDIM + n0 + bc2];
        }
        #pragma unroll
        for (int k = 0; k < 8; ++k) {
            float4 av = *reinterpret_cast<const float4*>(&su.m.As[k][ty * 4]);
            float4 bw = *reinterpret_cast<const float4*>(&su.m.Bs[k][tx * 4]);
            float aa[4] = {av.x, av.y, av.z, av.w};
            float bb4[4] = {bw.x, bw.y, bw.z, bw.w};
            #pragma unroll
            for (int i = 0; i < 4; ++i)
                #pragma unroll
                for (int jj = 0; jj < 4; ++jj)
                    acc[i][jj] = fmaf(aa[i], bb4[jj], acc[i][jj]);
        }
    }

    const bool isv = (n0 < VIS);
    float lpacc[4];
    #pragma unroll
    for (int i = 0; i < 4; ++i) {
        const int row = m0 + ty * 4 + i;
        float s = 0.f;
        #pragma unroll
        for (int jj = 0; jj < 4; ++jj) {
            const int n = n0 + tx * 4 + jj;
            float l = acc[i][jj] + lb[n];
            float e = eps[(size_t)row * NDIM + n];
            float z = 1.f / (1.f + expf(-(l + e) * 5.f));
            float p = 1.f / (1.f + expf(-l));
            float bb;
            if (isv) { zv[(size_t)row * VIS + n] = z; bb = bv[n]; }
            else     { zh[(size_t)row * HID + (n - VIS)] = z; bb = bh[n - VIS]; }
            s += logf(z * p + (1.f - z) * (1.f - p)) + z * bb;
        }
        lpacc[i] = s;
    }
    __syncthreads();
    #pragma unroll
    for (int i = 0; i < 4; ++i) su.m.red[(ty * 4 + i) * 33 + tx] = lpacc[i];
    __syncthreads();
    if (tid < 128) {
        float s = 0.f;
        #pragma unroll
        for (int x = 0; x < 32; ++x) s += su.m.red[tid * 33 + x];
        atomicAdd(&lp_row[m0 + tid], s);
    }
}

// ---------- GEMM2: fe quadratic term: rowsum((zeta_v @ w) * zeta_h) ----------
#define BM 128
#define BN 128
#define BK 8

__global__ __launch_bounds__(256) void gemm2_fe(
    const float* __restrict__ A, const float* __restrict__ B,
    const float* __restrict__ ZH, float* __restrict__ fe_row)
{
    __shared__ float As[BK][BM];
    __shared__ float Bs[BK][BN];
    __shared__ float red[BM * 17];
    const int tid = threadIdx.x;
    const int n0 = blockIdx.x * BN;
    const int m0 = blockIdx.y * BM;
    const int tx = tid & 15, ty = tid >> 4;
    const int ar = tid >> 1, ac = (tid & 1) * 4;
    const int br = tid >> 5, bc = (tid & 31) * 4;

    float acc[8][8];
    #pragma unroll
    for (int i = 0; i < 8; ++i)
        #pragma unroll
        for (int j = 0; j < 8; ++j) acc[i][j] = 0.f;

    for (int k0 = 0; k0 < 1024; k0 += BK) {
        float4 a = *reinterpret_cast<const float4*>(&A[(size_t)(m0 + ar) * 1024 + k0 + ac]);
        float4 b = *reinterpret_cast<const float4*>(&B[(size_t)(k0 + br) * 1024 + n0 + bc]);
        __syncthreads();
        As[ac + 0][ar] = a.x; As[ac + 1][ar] = a.y; As[ac + 2][ar] = a.z; As[ac + 3][ar] = a.w;
        *reinterpret_cast<float4*>(&Bs[br][bc]) = b;
        __syncthreads();
        #pragma unroll
        for (int k = 0; k < BK; ++k) {
            float av[8], bw[8];
            const float4* ap = reinterpret_cast<const float4*>(&As[k][ty * 8]);
            const float4* bp = reinterpret_cast<const float4*>(&Bs[k][tx * 8]);
            float4 a0 = ap[0], a1 = ap[1], b0 = bp[0], b1 = bp[1];
            av[0]=a0.x; av[1]=a0.y; av[2]=a0.z; av[3]=a0.w; av[4]=a1.x; av[5]=a1.y; av[6]=a1.z; av[7]=a1.w;
            bw[0]=b0.x; bw[1]=b0.y; bw[2]=b0.z; bw[3]=b0.w; bw[4]=b1.x; bw[5]=b1.y; bw[6]=b1.z; bw[7]=b1.w;
            #pragma unroll
            for (int i = 0; i < 8; ++i)
                #pragma unroll
                for (int j = 0; j < 8; ++j)
                    acc[i][j] = fmaf(av[i], bw[j], acc[i][j]);
        }
    }

    float feacc[8];
    #pragma unroll
    for (int i = 0; i < 8; ++i) {
        const int row = m0 + ty * 8 + i;
        float s = 0.f;
        #pragma unroll
        for (int j = 0; j < 8; ++j) {
            const int n = n0 + tx * 8 + j;
            s += acc[i][j] * ZH[(size_t)row * HID + n];
        }
        feacc[i] = s;
    }
    __syncthreads();
    #pragma unroll
    for (int i = 0; i < 8; ++i) red[(ty * 8 + i) * 17 + tx] = feacc[i];
    __syncthreads();
    if (tid < BM) {
        float s = 0.f;
        #pragma unroll
        for (int x = 0; x < 16; ++x) s += red[tid * 17 + x];
        atomicAdd(&fe_row[m0 + tid], s);
    }
}

__global__ __launch_bounds__(256) void final_kl(
    const float* __restrict__ lp_row, const float* __restrict__ fe_row,
    const double* __restrict__ fe_sum, float* __restrict__ out_kl)
{
    __shared__ double dred[256];
    const int tid = threadIdx.x;
    double acc = 0.0;
    for (int r = tid; r < NROW; r += 256)
        acc += (double)lp_row[r] + (double)fe_row[r];
    dred[tid] = acc;
    __syncthreads();
    for (int off = 128; off > 0; off >>= 1) {
        if (tid < off) dred[tid] += dred[tid + off];
        __syncthreads();
    }
    if (tid == 0) out_kl[0] = (float)(dred[0] / 8192.0 - fe_sum[0] / 10.0);
}

extern "C" void kernel_launch(void* const* d_in, const int* in_sizes, int n_in,
                              void* d_out, int out_size, void* d_ws, size_t ws_size,
                              hipStream_t stream)
{
    const float* vecs   = (const float*)d_in[0];
    const float* lw     = (const float*)d_in[1];
    const float* lb     = (const float*)d_in[2];
    const float* w      = (const float*)d_in[3];
    const float* bv     = (const float*)d_in[4];
    const float* bh     = (const float*)d_in[5];
    const float* eps    = (const float*)d_in[6];
    const float* u_init = (const float*)d_in[7];
    const float* u_h    = (const float*)d_in[8];
    const float* u_v    = (const float*)d_in[9];

    float* out    = (float*)d_out;
    float* zv     = out;
    float* zh     = out + (size_t)NROW * VIS;
    float* out_kl = out + (size_t)NROW * 2048;

    const size_t thr_sz = (size_t)NSTEPS * 1024 * 8;      // 16.47 MB each
    const size_t pre_need = (4u << 20) + 2 * thr_sz + 65536 + 64;
    const int use_pre = (ws_size >= pre_need) ? 1 : 0;

    char* ws = (char*)d_ws;
    float*  wT   = (float*)ws;                            // 4 MB
    double* thrH = use_pre ? (double*)(ws + (4u << 20)) : nullptr;
    double* thrV = use_pre ? (double*)(ws + (4u << 20) + thr_sz) : nullptr;
    size_t tail  = (4u << 20) + (use_pre ? 2 * thr_sz : 0);
    float*  lp_row = (float*)(ws + tail);                 // 8192 f32
    float*  fe_row = lp_row + 8192;                       // 8192 f32
    double* fes    = (double*)(ws + tail + 65536);

    init_zero<<<64, 256, 0, stream>>>(lp_row, 16384);     // lp_row + fe_row
    transpose_w_k<<<dim3(32, 32), 256, 0, stream>>>(w, wT);
    if (use_pre)
        prep_thr<<<(NSTEPS * 1024 + 255) / 256, 256, 0, stream>>>(u_h, u_v, bh, bv, thrH, thrV);
    fused_k<<<1 + 1024, 1024, 0, stream>>>(
        w, wT, bv, bh, u_init, u_h, u_v, fes, thrH, thrV, use_pre,
        vecs, lw, lb, eps, zv, zh, lp_row);
    gemm2_fe<<<dim3(8, 64), 256, 0, stream>>>(zv, w, zh, fe_row);
    final_kl<<<1, 256, 0, stream>>>(lp_row, fe_row, fes, out_kl);
}

// Round 7
// 5212.584 us; speedup vs baseline: 2.3494x; 2.3494x over previous
//
#include <hip/hip_runtime.h>
#include <math.h>

#define VIS 1024
#define HID 1024
#define NROW 8192
#define KDIM 2048
#define NDIM 2048
#define NSTEPS 2010
#define KLS 10

__global__ __launch_bounds__(256) void init_zero(float* p, int n) {
    int i = blockIdx.x * 256 + threadIdx.x;
    if (i < n) p[i] = 0.f;
}

__global__ __launch_bounds__(256) void transpose_w_k(const float* __restrict__ w,
                                                     float* __restrict__ wT) {
    __shared__ float tile[32][33];
    int bx = blockIdx.x * 32, by = blockIdx.y * 32;
    int tx = threadIdx.x & 31, ty = threadIdx.x >> 5;  // ty 0..7
    #pragma unroll
    for (int m = 0; m < 4; ++m) {
        int y = by + ty + m * 8;
        tile[ty + m * 8][tx] = w[(size_t)y * 1024 + bx + tx];
    }
    __syncthreads();
    #pragma unroll
    for (int m = 0; m < 4; ++m) {
        int y = bx + ty + m * 8;
        wT[(size_t)y * 1024 + by + tx] = tile[tx][ty + m * 8];
    }
}

// thresholds thr = log(u) - log1p(-u) - bias, f64, computed chip-wide
__global__ __launch_bounds__(256) void prep_thr(
    const float* __restrict__ u_h, const float* __restrict__ u_v,
    const float* __restrict__ bh, const float* __restrict__ bv,
    double* __restrict__ thrH, double* __restrict__ thrV)
{
    int i = blockIdx.x * 256 + threadIdx.x;
    if (i < NSTEPS * 1024) {
        int jj = i & 1023;
        double uh = (double)u_h[i];
        thrH[i] = log(uh) - log1p(-uh) - (double)bh[jj];
        double uv = (double)u_v[i];
        thrV[i] = log(uv) - log1p(-uv) - (double)bv[jj];
    }
}

// ---------------- shared-memory union for the fused kernel ----------------
struct SGibbs {
    int wcnt[16] __attribute__((aligned(16)));    // (wave,k) flip counts
    int sidx[1040] __attribute__((aligned(16)));  // flip list: (row<<12)|(valid<<1)|bit
    double redd[4];
};
struct SMm1 {
    float As[8][128];
    float Bs[8][128];
    float red[128 * 17];
};
union SharedU { SGibbs g; SMm1 m; };

// 4-flag list build (256 threads / 4 waves; thread owns units 4t..4t+3)
__device__ __forceinline__ int build4(SGibbs& sg, const bool* fl, const bool* nb,
                                      int t, int wv, int lane, int tid) {
    unsigned long long m[4];
    #pragma unroll
    for (int k = 0; k < 4; ++k) m[k] = __ballot(fl[k]);
    if (lane == 0) {
        #pragma unroll
        for (int k = 0; k < 4; ++k) sg.wcnt[wv * 4 + k] = __popcll(m[k]);
    }
    __syncthreads();   // B1: counts ready; also guards prev-phase sidx reads
    const int4* wc = (const int4*)sg.wcnt;
    int4 c0 = wc[0], c1 = wc[1], c2 = wc[2], c3 = wc[3];
    int cs[16] = {c0.x, c0.y, c0.z, c0.w, c1.x, c1.y, c1.z, c1.w,
                  c2.x, c2.y, c2.z, c2.w, c3.x, c3.y, c3.z, c3.w};
    int n = 0, offk[4] = {0, 0, 0, 0};
    const int base4 = wv * 4;
    #pragma unroll
    for (int u = 0; u < 16; ++u) {
        int cu = cs[u];
        #pragma unroll
        for (int k = 0; k < 4; ++k) offk[k] += (u < base4 + k) ? cu : 0;
        n += cu;
    }
    unsigned long long below = (1ull << lane) - 1ull;
    #pragma unroll
    for (int k = 0; k < 4; ++k)
        if (fl[k])
            sg.sidx[offk[k] + __popcll(m[k] & below)] =
                (((4 * t + k)) << 12) | 2 | (nb[k] ? 1 : 0);
    int npad = (n + 7) & ~7;
    if (tid < npad - n) sg.sidx[n + tid] = 0;      // pad: contributes 0
    __syncthreads();   // B2: list ready
    return npad;
}

// double-buffered 8-entry apply: dwordx4 per thread per entry, 4 f64 FMA
#define LOADE(base, e, v)                                                  \
    {                                                                      \
        int4 _a = *(const int4*)&sg.sidx[(base)];                          \
        int4 _b = *(const int4*)&sg.sidx[(base) + 4];                      \
        e[0] = _a.x; e[1] = _a.y; e[2] = _a.z; e[3] = _a.w;                \
        e[4] = _b.x; e[5] = _b.y; e[6] = _b.z; e[7] = _b.w;                \
        _Pragma("unroll")                                                  \
        for (int _q = 0; _q < 8; ++_q)                                     \
            v[_q] = *(const float4*)(Mb + (e[_q] & 0x3FF000));             \
    }
#define PROC(e, v)                                                         \
    {                                                                      \
        _Pragma("unroll")                                                  \
        for (int _q = 0; _q < 8; ++_q) {                                   \
            double _s = (e[_q] & 2) ? ((e[_q] & 1) ? 1.0 : -1.0) : 0.0;    \
            dot[0] = fma(_s, (double)v[_q].x, dot[0]);                     \
            dot[1] = fma(_s, (double)v[_q].y, dot[1]);                     \
            dot[2] = fma(_s, (double)v[_q].z, dot[2]);                     \
            dot[3] = fma(_s, (double)v[_q].w, dot[3]);                     \
        }                                                                  \
    }

__device__ __forceinline__ void apply_ph(double* dot, const SGibbs& sg, int npad,
                                         const char* Mb) {
    int eA[8], eB[8];
    float4 vA[8], vB[8];
    LOADE(0, eA, vA);
    for (int i = 8; i < npad; i += 8) {
        LOADE(i, eB, vB);     // issue next chunk's loads
        PROC(eA, vA);
        #pragma unroll
        for (int q = 0; q < 8; ++q) { eA[q] = eB[q]; vA[q] = vB[q]; }
    }
    PROC(eA, vA);
}

// ---- fused: block 0 = Gibbs chain (256 thr, 4 waves, flip-incremental f64);
// ----        blocks 1..1024 = GEMM1 + zeta + log-posterior epilogue.
__global__ __launch_bounds__(256) void fused_k(
    const float* __restrict__ w, const float* __restrict__ wT,
    const float* __restrict__ bv, const float* __restrict__ bh,
    const float* __restrict__ u_init, const float* __restrict__ u_h,
    const float* __restrict__ u_v, double* __restrict__ fes,
    const double* __restrict__ thrHp, const double* __restrict__ thrVp, int use_pre,
    const float* __restrict__ A, const float* __restrict__ B,
    const float* __restrict__ lb, const float* __restrict__ eps,
    float* __restrict__ zv, float* __restrict__ zh, float* __restrict__ lp_row)
{
    __shared__ SharedU su;
    const int tid = threadIdx.x;

    if (blockIdx.x == 0) {
        // ======================= GIBBS (single WG, 4 waves) =======================
        SGibbs& sg = su.g;
        const int t4 = tid;                       // thread owns cols 4*t4 .. 4*t4+3
        const int wv = tid >> 6, lane = tid & 63;
        const char* wjb  = (const char*)w  + (size_t)t4 * 16;
        const char* wTjb = (const char*)wT + (size_t)t4 * 16;
        double doth[4] = {0, 0, 0, 0}, dotv[4] = {0, 0, 0, 0};
        double fe_acc = 0.0;

        bool mv[4], mh[4] = {false, false, false, false};
        {
            float4 ui = *(const float4*)&u_init[4 * t4];
            mv[0] = ui.x >= 0.5f; mv[1] = ui.y >= 0.5f;
            mv[2] = ui.z >= 0.5f; mv[3] = ui.w >= 0.5f;
        }
        // thresholds, one phase ahead
        double thH[4], thV[4];
        #pragma unroll
        for (int k = 0; k < 4; ++k) {
            if (use_pre) { thH[k] = thrHp[4 * t4 + k]; thV[k] = thrVp[4 * t4 + k]; }
            else {
                double uh = (double)u_h[4 * t4 + k];
                thH[k] = log(uh) - log1p(-uh) - (double)bh[4 * t4 + k];
                double uv = (double)u_v[4 * t4 + k];
                thV[k] = log(uv) - log1p(-uv) - (double)bv[4 * t4 + k];
            }
        }
        {   // initial doth = sv0 @ w  (flips vs virtual all-zero v-state)
            bool nb1[4] = {true, true, true, true};
            int np0 = build4(sg, mv, nb1, t4, wv, lane, tid);
            { double* dot = doth; const char* Mb = wjb; apply_ph(dot, sg, np0, Mb); }
        }

        for (int t = 0; t < NSTEPS; ++t) {
            // ---- phase a: sh_k = (doth_k <= thH_k); flipped H rows update dotv via wT
            bool nh[4], flH[4];
            #pragma unroll
            for (int k = 0; k < 4; ++k) { nh[k] = (doth[k] <= thH[k]); flH[k] = (nh[k] != mh[k]); mh[k] = nh[k]; }
            // prefetch next-step H thresholds
            double thHn[4];
            if (t + 1 < NSTEPS) {
                if (use_pre) {
                    double2 a = *(const double2*)&thrHp[(size_t)(t + 1) * 1024 + 4 * t4];
                    double2 b = *(const double2*)&thrHp[(size_t)(t + 1) * 1024 + 4 * t4 + 2];
                    thHn[0] = a.x; thHn[1] = a.y; thHn[2] = b.x; thHn[3] = b.y;
                } else {
                    #pragma unroll
                    for (int k = 0; k < 4; ++k) {
                        double u = (double)u_h[(size_t)(t + 1) * 1024 + 4 * t4 + k];
                        thHn[k] = log(u) - log1p(-u) - (double)bh[4 * t4 + k];
                    }
                }
            }
            int np = build4(sg, flH, nh, t4, wv, lane, tid);
            { double* dot = dotv; const char* Mb = wTjb; apply_ph(dot, sg, np, Mb); }

            // ---- phase b: sv_k = (dotv_k <= thV_k); flipped V rows update doth via w
            bool nv[4], flV[4];
            #pragma unroll
            for (int k = 0; k < 4; ++k) { nv[k] = (dotv[k] <= thV[k]); flV[k] = (nv[k] != mv[k]); mv[k] = nv[k]; }
            // prefetch next-step V thresholds
            if (t + 1 < NSTEPS) {
                if (use_pre) {
                    double2 a = *(const double2*)&thrVp[(size_t)(t + 1) * 1024 + 4 * t4];
                    double2 b = *(const double2*)&thrVp[(size_t)(t + 1) * 1024 + 4 * t4 + 2];
                    thV[0] = a.x; thV[1] = a.y; thV[2] = b.x; thV[3] = b.y;
                } else {
                    #pragma unroll
                    for (int k = 0; k < 4; ++k) {
                        double u = (double)u_v[(size_t)(t + 1) * 1024 + 4 * t4 + k];
                        thV[k] = log(u) - log1p(-u) - (double)bv[4 * t4 + k];
                    }
                }
                #pragma unroll
                for (int k = 0; k < 4; ++k) thH[k] = thHn[k];
            }
            np = build4(sg, flV, nv, t4, wv, lane, tid);
            { double* dot = doth; const char* Mb = wjb; apply_ph(dot, sg, np, Mb); }

            // ---- sample free energy: fe = sv.bv + sh.(bh + doth) ----
            if (t >= NSTEPS - KLS) {
                double c = 0.0;
                #pragma unroll
                for (int k = 0; k < 4; ++k) {
                    double bvk = (double)bv[4 * t4 + k], bhk = (double)bh[4 * t4 + k];
                    c += (nv[k] ? bvk : 0.0) + (nh[k] ? (bhk + doth[k]) : 0.0);
                }
                #pragma unroll
                for (int o = 32; o > 0; o >>= 1) c += __shfl_down(c, o);
                if (lane == 0) sg.redd[wv] = c;
                __syncthreads();
                if (tid == 0)
                    fe_acc += sg.redd[0] + sg.redd[1] + sg.redd[2] + sg.redd[3];
                __syncthreads();
            }
        }
        if (tid == 0) fes[0] = fe_acc;
        return;
    }

    // ======================= GEMM1 (+ zeta + log-posterior) =======================
    const int gid = blockIdx.x - 1;
    const int n0 = (gid & 15) * 128;
    const int m0 = (gid >> 4) * 128;
    const int tx = tid & 15, ty = tid >> 4;
    const int ar = tid >> 1, ac = (tid & 1) * 4;
    const int br = tid >> 5, bc = (tid & 31) * 4;

    float acc[8][8];
    #pragma unroll
    for (int i = 0; i < 8; ++i)
        #pragma unroll
        for (int j = 0; j < 8; ++j) acc[i][j] = 0.f;

    float4 a_reg = *reinterpret_cast<const float4*>(&A[(size_t)(m0 + ar) * KDIM + ac]);
    float4 b_reg = *reinterpret_cast<const float4*>(&B[(size_t)br * NDIM + n0 + bc]);
    for (int k0 = 0; k0 < KDIM; k0 += 8) {
        __syncthreads();
        su.m.As[ac + 0][ar] = a_reg.x; su.m.As[ac + 1][ar] = a_reg.y;
        su.m.As[ac + 2][ar] = a_reg.z; su.m.As[ac + 3][ar] = a_reg.w;
        *reinterpret_cast<float4*>(&su.m.Bs[br][bc]) = b_reg;
        __syncthreads();
        if (k0 + 8 < KDIM) {
            a_reg = *reinterpret_cast<const float4*>(&A[(size_t)(m0 + ar) * KDIM + k0 + 8 + ac]);
            b_reg = *reinterpret_cast<const float4*>(&B[(size_t)(k0 + 8 + br) * NDIM + n0 + bc]);
        }
        #pragma unroll
        for (int k = 0; k < 8; ++k) {
            float av[8], bw[8];
            const float4* ap = reinterpret_cast<const float4*>(&su.m.As[k][ty * 8]);
            const float4* bp = reinterpret_cast<const float4*>(&su.m.Bs[k][tx * 8]);
            float4 a0 = ap[0], a1 = ap[1], b0 = bp[0], b1 = bp[1];
            av[0]=a0.x; av[1]=a0.y; av[2]=a0.z; av[3]=a0.w; av[4]=a1.x; av[5]=a1.y; av[6]=a1.z; av[7]=a1.w;
            bw[0]=b0.x; bw[1]=b0.y; bw[2]=b0.z; bw[3]=b0.w; bw[4]=b1.x; bw[5]=b1.y; bw[6]=b1.z; bw[7]=b1.w;
            #pragma unroll
            for (int i = 0; i < 8; ++i)
                #pragma unroll
                for (int j = 0; j < 8; ++j)
                    acc[i][j] = fmaf(av[i], bw[j], acc[i][j]);
        }
    }

    const bool isv = (n0 < VIS);
    float lpacc[8];
    #pragma unroll
    for (int i = 0; i < 8; ++i) {
        const int row = m0 + ty * 8 + i;
        float s = 0.f;
        #pragma unroll
        for (int j = 0; j < 8; ++j) {
            const int n = n0 + tx * 8 + j;
            float l = acc[i][j] + lb[n];
            float e = eps[(size_t)row * NDIM + n];
            float z = 1.f / (1.f + expf(-(l + e) * 5.f));
            float p = 1.f / (1.f + expf(-l));
            float bb;
            if (isv) { zv[(size_t)row * VIS + n] = z; bb = bv[n]; }
            else     { zh[(size_t)row * HID + (n - VIS)] = z; bb = bh[n - VIS]; }
            s += logf(z * p + (1.f - z) * (1.f - p)) + z * bb;
        }
        lpacc[i] = s;
    }
    __syncthreads();
    #pragma unroll
    for (int i = 0; i < 8; ++i) su.m.red[(ty * 8 + i) * 17 + tx] = lpacc[i];
    __syncthreads();
    if (tid < 128) {
        float s = 0.f;
        #pragma unroll
        for (int x = 0; x < 16; ++x) s += su.m.red[tid * 17 + x];
        atomicAdd(&lp_row[m0 + tid], s);
    }
}

// ---------- GEMM2: fe quadratic term: rowsum((zeta_v @ w) * zeta_h) ----------
#define BM 128
#define BN 128
#define BK 8

__global__ __launch_bounds__(256) void gemm2_fe(
    const float* __restrict__ A, const float* __restrict__ B,
    const float* __restrict__ ZH, float* __restrict__ fe_row)
{
    __shared__ float As[BK][BM];
    __shared__ float Bs[BK][BN];
    __shared__ float red[BM * 17];
    const int tid = threadIdx.x;
    const int n0 = blockIdx.x * BN;
    const int m0 = blockIdx.y * BM;
    const int tx = tid & 15, ty = tid >> 4;
    const int ar = tid >> 1, ac = (tid & 1) * 4;
    const int br = tid >> 5, bc = (tid & 31) * 4;

    float acc[8][8];
    #pragma unroll
    for (int i = 0; i < 8; ++i)
        #pragma unroll
        for (int j = 0; j < 8; ++j) acc[i][j] = 0.f;

    for (int k0 = 0; k0 < 1024; k0 += BK) {
        float4 a = *reinterpret_cast<const float4*>(&A[(size_t)(m0 + ar) * 1024 + k0 + ac]);
        float4 b = *reinterpret_cast<const float4*>(&B[(size_t)(k0 + br) * 1024 + n0 + bc]);
        __syncthreads();
        As[ac + 0][ar] = a.x; As[ac + 1][ar] = a.y; As[ac + 2][ar] = a.z; As[ac + 3][ar] = a.w;
        *reinterpret_cast<float4*>(&Bs[br][bc]) = b;
        __syncthreads();
        #pragma unroll
        for (int k = 0; k < BK; ++k) {
            float av[8], bw[8];
            const float4* ap = reinterpret_cast<const float4*>(&As[k][ty * 8]);
            const float4* bp = reinterpret_cast<const float4*>(&Bs[k][tx * 8]);
            float4 a0 = ap[0], a1 = ap[1], b0 = bp[0], b1 = bp[1];
            av[0]=a0.x; av[1]=a0.y; av[2]=a0.z; av[3]=a0.w; av[4]=a1.x; av[5]=a1.y; av[6]=a1.z; av[7]=a1.w;
            bw[0]=b0.x; bw[1]=b0.y; bw[2]=b0.z; bw[3]=b0.w; bw[4]=b1.x; bw[5]=b1.y; bw[6]=b1.z; bw[7]=b1.w;
            #pragma unroll
            for (int i = 0; i < 8; ++i)
                #pragma unroll
                for (int j = 0; j < 8; ++j)
                    acc[i][j] = fmaf(av[i], bw[j], acc[i][j]);
        }
    }

    float feacc[8];
    #pragma unroll
    for (int i = 0; i < 8; ++i) {
        const int row = m0 + ty * 8 + i;
        float s = 0.f;
        #pragma unroll
        for (int j = 0; j < 8; ++j) {
            const int n = n0 + tx * 8 + j;
            s += acc[i][j] * ZH[(size_t)row * HID + n];
        }
        feacc[i] = s;
    }
    __syncthreads();
    #pragma unroll
    for (int i = 0; i < 8; ++i) red[(ty * 8 + i) * 17 + tx] = feacc[i];
    __syncthreads();
    if (tid < BM) {
        float s = 0.f;
        #pragma unroll
        for (int x = 0; x < 16; ++x) s += red[tid * 17 + x];
        atomicAdd(&fe_row[m0 + tid], s);
    }
}

__global__ __launch_bounds__(256) void final_kl(
    const float* __restrict__ lp_row, const float* __restrict__ fe_row,
    const double* __restrict__ fe_sum, float* __restrict__ out_kl)
{
    __shared__ double dred[256];
    const int tid = threadIdx.x;
    double acc = 0.0;
    for (int r = tid; r < NROW; r += 256)
        acc += (double)lp_row[r] + (double)fe_row[r];
    dred[tid] = acc;
    __syncthreads();
    for (int off = 128; off > 0; off >>= 1) {
        if (tid < off) dred[tid] += dred[tid + off];
        __syncthreads();
    }
    if (tid == 0) out_kl[0] = (float)(dred[0] / 8192.0 - fe_sum[0] / 10.0);
}

extern "C" void kernel_launch(void* const* d_in, const int* in_sizes, int n_in,
                              void* d_out, int out_size, void* d_ws, size_t ws_size,
                              hipStream_t stream)
{
    const float* vecs   = (const float*)d_in[0];
    const float* lw     = (const float*)d_in[1];
    const float* lb     = (const float*)d_in[2];
    const float* w      = (const float*)d_in[3];
    const float* bv     = (const float*)d_in[4];
    const float* bh     = (const float*)d_in[5];
    const float* eps    = (const float*)d_in[6];
    const float* u_init = (const float*)d_in[7];
    const float* u_h    = (const float*)d_in[8];
    const float* u_v    = (const float*)d_in[9];

    float* out    = (float*)d_out;
    float* zv     = out;
    float* zh     = out + (size_t)NROW * VIS;
    float* out_kl = out + (size_t)NROW * 2048;

    const size_t thr_sz = (size_t)NSTEPS * 1024 * 8;      // 16.47 MB each
    const size_t pre_need = (4u << 20) + 2 * thr_sz + 65536 + 64;
    const int use_pre = (ws_size >= pre_need) ? 1 : 0;

    char* ws = (char*)d_ws;
    float*  wT   = (float*)ws;                            // 4 MB
    double* thrH = use_pre ? (double*)(ws + (4u << 20)) : nullptr;
    double* thrV = use_pre ? (double*)(ws + (4u << 20) + thr_sz) : nullptr;
    size_t tail  = (4u << 20) + (use_pre ? 2 * thr_sz : 0);
    float*  lp_row = (float*)(ws + tail);                 // 8192 f32
    float*  fe_row = lp_row + 8192;                       // 8192 f32
    double* fes    = (double*)(ws + tail + 65536);

    init_zero<<<64, 256, 0, stream>>>(lp_row, 16384);     // lp_row + fe_row
    transpose_w_k<<<dim3(32, 32), 256, 0, stream>>>(w, wT);
    if (use_pre)
        prep_thr<<<(NSTEPS * 1024 + 255) / 256, 256, 0, stream>>>(u_h, u_v, bh, bv, thrH, thrV);
    fused_k<<<1 + 1024, 256, 0, stream>>>(
        w, wT, bv, bh, u_init, u_h, u_v, fes, thrH, thrV, use_pre,
        vecs, lw, lb, eps, zv, zh, lp_row);
    gemm2_fe<<<dim3(8, 64), 256, 0, stream>>>(zv, w, zh, fe_row);
    final_kl<<<1, 256, 0, stream>>>(lp_row, fe_row, fes, out_kl);
}

// Round 8
// 4424.566 us; speedup vs baseline: 2.7679x; 1.1781x over previous
//
#include <hip/hip_runtime.h>
#include <math.h>

#define VIS 1024
#define HID 1024
#define NROW 8192
#define KDIM 2048
#define NDIM 2048
#define NSTEPS 2010
#define KLS 10

__global__ __launch_bounds__(256) void init_zero(float* p, int n) {
    int i = blockIdx.x * 256 + threadIdx.x;
    if (i < n) p[i] = 0.f;
}

__global__ __launch_bounds__(256) void transpose_w_k(const float* __restrict__ w,
                                                     float* __restrict__ wT) {
    __shared__ float tile[32][33];
    int bx = blockIdx.x * 32, by = blockIdx.y * 32;
    int tx = threadIdx.x & 31, ty = threadIdx.x >> 5;  // ty 0..7
    #pragma unroll
    for (int m = 0; m < 4; ++m) {
        int y = by + ty + m * 8;
        tile[ty + m * 8][tx] = w[(size_t)y * 1024 + bx + tx];
    }
    __syncthreads();
    #pragma unroll
    for (int m = 0; m < 4; ++m) {
        int y = bx + ty + m * 8;
        wT[(size_t)y * 1024 + by + tx] = tile[tx][ty + m * 8];
    }
}

// thresholds thr = log(u) - log1p(-u) - bias, f64, computed chip-wide
__global__ __launch_bounds__(256) void prep_thr(
    const float* __restrict__ u_h, const float* __restrict__ u_v,
    const float* __restrict__ bh, const float* __restrict__ bv,
    double* __restrict__ thrH, double* __restrict__ thrV)
{
    int i = blockIdx.x * 256 + threadIdx.x;
    if (i < NSTEPS * 1024) {
        int jj = i & 1023;
        double uh = (double)u_h[i];
        thrH[i] = log(uh) - log1p(-uh) - (double)bh[jj];
        double uv = (double)u_v[i];
        thrV[i] = log(uv) - log1p(-uv) - (double)bv[jj];
    }
}

// ---------------- shared-memory union for the fused kernel ----------------
struct SGibbs {
    int wcnt[4] __attribute__((aligned(16)));     // per-wave flip counts
    int sidx[1040] __attribute__((aligned(16)));  // flip list: (row<<12)|(valid<<1)|bit
    double redd[4];
};
struct SMm1 {
    float As[8][128];
    float Bs[8][128];
    float red[128 * 17];
};
union SharedU { SGibbs g; SMm1 m; };

// ascending-row flip list (row = 4*tid+k; lex order (wv,lane,k) == ascending row).
// NOTE: list order defines the f64 accumulation order — keep ASCENDING (R4-R6
// numerics: 0 decision flips vs the np f64 reference; interleaved order flipped one).
__device__ __forceinline__ int build4(SGibbs& sg, const bool* fl, const bool* nb,
                                      int wv, int lane, int tid) {
    unsigned long long m0 = __ballot(fl[0]), m1 = __ballot(fl[1]),
                       m2 = __ballot(fl[2]), m3 = __ballot(fl[3]);
    if (lane == 0)
        sg.wcnt[wv] = __popcll(m0) + __popcll(m1) + __popcll(m2) + __popcll(m3);
    __syncthreads();   // B1: counts ready; also guards prev-phase sidx reads
    int c0 = sg.wcnt[0], c1 = sg.wcnt[1], c2 = sg.wcnt[2], c3 = sg.wcnt[3];
    int n = c0 + c1 + c2 + c3;
    int off = (wv > 0 ? c0 : 0) + (wv > 1 ? c1 : 0) + (wv > 2 ? c2 : 0);
    unsigned long long below = (1ull << lane) - 1ull;
    int base = off + __popcll(m0 & below) + __popcll(m1 & below)
                   + __popcll(m2 & below) + __popcll(m3 & below);
    const int r0 = tid << 2;
    if (fl[0]) sg.sidx[base++] = ((r0    ) << 12) | 2 | (nb[0] ? 1 : 0);
    if (fl[1]) sg.sidx[base++] = ((r0 + 1) << 12) | 2 | (nb[1] ? 1 : 0);
    if (fl[2]) sg.sidx[base++] = ((r0 + 2) << 12) | 2 | (nb[2] ? 1 : 0);
    if (fl[3]) sg.sidx[base++] = ((r0 + 3) << 12) | 2 | (nb[3] ? 1 : 0);
    int npad = (n + 7) & ~7;
    if (tid < npad - n) sg.sidx[n + tid] = 0;      // pad: contributes 0
    __syncthreads();   // B2: list ready
    return npad;
}

// 8-entry chunk: dwordx4 per thread per entry, 4 f64 FMA per entry
#define LOADE(base, e, v)                                                  \
    {                                                                      \
        int4 _a = *(const int4*)&sg.sidx[(base)];                          \
        int4 _b = *(const int4*)&sg.sidx[(base) + 4];                      \
        e[0] = _a.x; e[1] = _a.y; e[2] = _a.z; e[3] = _a.w;                \
        e[4] = _b.x; e[5] = _b.y; e[6] = _b.z; e[7] = _b.w;                \
        _Pragma("unroll")                                                  \
        for (int _q = 0; _q < 8; ++_q)                                     \
            v[_q] = *(const float4*)(Mb + (e[_q] & 0x3FF000));             \
    }
#define PROC(e, v)                                                         \
    {                                                                      \
        _Pragma("unroll")                                                  \
        for (int _q = 0; _q < 8; ++_q) {                                   \
            double _s = (e[_q] & 2) ? ((e[_q] & 1) ? 1.0 : -1.0) : 0.0;    \
            dot[0] = fma(_s, (double)v[_q].x, dot[0]);                     \
            dot[1] = fma(_s, (double)v[_q].y, dot[1]);                     \
            dot[2] = fma(_s, (double)v[_q].z, dot[2]);                     \
            dot[3] = fma(_s, (double)v[_q].w, dot[3]);                     \
        }                                                                  \
    }

// 2-deep pipelined apply + 3rd buffer for the tail chunk; PROC order ascending.
__device__ __forceinline__ void apply_ph(double* dot, const SGibbs& sg, int npad,
                                         const char* Mb) {
    int nch = npad >> 3;
    if (nch == 0) return;
    int e0[8], e1[8], e2[8];
    float4 v0[8], v1[8], v2[8];
    LOADE(0, e0, v0);
    if (nch > 1) LOADE(8, e1, v1);
    int c = 0;
    for (; c + 3 < nch; c += 2) {
        PROC(e0, v0); LOADE((c + 2) * 8, e0, v0);
        PROC(e1, v1); LOADE((c + 3) * 8, e1, v1);
    }
    int rem = nch - c;                 // 1..3
    if (rem == 3) LOADE((c + 2) * 8, e2, v2);
    PROC(e0, v0);
    if (rem >= 2) PROC(e1, v1);
    if (rem == 3) PROC(e2, v2);
}

// ---- fused: block 0 = Gibbs chain (256 thr, 4 waves, flip-incremental f64);
// ----        blocks 1..1024 = GEMM1 + zeta + log-posterior epilogue.
__global__ __launch_bounds__(256) void fused_k(
    const float* __restrict__ w, const float* __restrict__ wT,
    const float* __restrict__ bv, const float* __restrict__ bh,
    const float* __restrict__ u_init, const float* __restrict__ u_h,
    const float* __restrict__ u_v, double* __restrict__ fes,
    const double* __restrict__ thrHp, const double* __restrict__ thrVp, int use_pre,
    const float* __restrict__ A, const float* __restrict__ B,
    const float* __restrict__ lb, const float* __restrict__ eps,
    float* __restrict__ zv, float* __restrict__ zh, float* __restrict__ lp_row)
{
    __shared__ SharedU su;
    const int tid = threadIdx.x;

    if (blockIdx.x == 0) {
        // ======================= GIBBS (single WG, 4 waves) =======================
        SGibbs& sg = su.g;
        const int t4 = tid;                       // thread owns cols 4*t4 .. 4*t4+3
        const int wv = tid >> 6, lane = tid & 63;
        const char* wjb  = (const char*)w  + (size_t)t4 * 16;
        const char* wTjb = (const char*)wT + (size_t)t4 * 16;
        double doth[4] = {0, 0, 0, 0}, dotv[4] = {0, 0, 0, 0};
        double fe_acc = 0.0;

        bool mv[4], mh[4] = {false, false, false, false};
        {
            float4 ui = *(const float4*)&u_init[4 * t4];
            mv[0] = ui.x >= 0.5f; mv[1] = ui.y >= 0.5f;
            mv[2] = ui.z >= 0.5f; mv[3] = ui.w >= 0.5f;
        }
        // step-0 thresholds (one-time cold load before the loop)
        double thH[4], thV[4];
        #pragma unroll
        for (int k = 0; k < 4; ++k) {
            if (use_pre) { thH[k] = thrHp[4 * t4 + k]; thV[k] = thrVp[4 * t4 + k]; }
            else {
                double uh = (double)u_h[4 * t4 + k];
                thH[k] = log(uh) - log1p(-uh) - (double)bh[4 * t4 + k];
                double uv = (double)u_v[4 * t4 + k];
                thV[k] = log(uv) - log1p(-uv) - (double)bv[4 * t4 + k];
            }
        }
        {   // initial doth = sv0 @ w  (flips vs virtual all-zero v-state)
            bool nb1[4] = {true, true, true, true};
            int np0 = build4(sg, mv, nb1, wv, lane, tid);
            { double* dot = doth; const char* Mb = wjb; apply_ph(dot, sg, np0, Mb); }
        }

        for (int t = 0; t < NSTEPS; ++t) {
            // ---- phase a: sh_k = (doth_k <= thH_k) ----
            bool nh[4], flH[4];
            #pragma unroll
            for (int k = 0; k < 4; ++k) { nh[k] = (doth[k] <= thH[k]); flH[k] = (nh[k] != mh[k]); mh[k] = nh[k]; }
            int np = build4(sg, flH, nh, wv, lane, tid);
            // t+1 H-threshold prefetch AFTER B2: completes during apply; no
            // vmcnt(0) drain at the next barrier (issued-before-barrier stall).
            double thHn[4] = {0, 0, 0, 0};
            if (t + 1 < NSTEPS) {
                if (use_pre) {
                    double2 a = *(const double2*)&thrHp[(size_t)(t + 1) * 1024 + 4 * t4];
                    double2 b = *(const double2*)&thrHp[(size_t)(t + 1) * 1024 + 4 * t4 + 2];
                    thHn[0] = a.x; thHn[1] = a.y; thHn[2] = b.x; thHn[3] = b.y;
                } else {
                    #pragma unroll
                    for (int k = 0; k < 4; ++k) {
                        double u = (double)u_h[(size_t)(t + 1) * 1024 + 4 * t4 + k];
                        thHn[k] = log(u) - log1p(-u) - (double)bh[4 * t4 + k];
                    }
                }
            }
            { double* dot = dotv; const char* Mb = wTjb; apply_ph(dot, sg, np, Mb); }

            // ---- phase b: sv_k = (dotv_k <= thV_k) ----
            bool nv[4], flV[4];
            #pragma unroll
            for (int k = 0; k < 4; ++k) { nv[k] = (dotv[k] <= thV[k]); flV[k] = (nv[k] != mv[k]); mv[k] = nv[k]; }
            np = build4(sg, flV, nv, wv, lane, tid);
            double thVn[4] = {0, 0, 0, 0};
            if (t + 1 < NSTEPS) {
                if (use_pre) {
                    double2 a = *(const double2*)&thrVp[(size_t)(t + 1) * 1024 + 4 * t4];
                    double2 b = *(const double2*)&thrVp[(size_t)(t + 1) * 1024 + 4 * t4 + 2];
                    thVn[0] = a.x; thVn[1] = a.y; thVn[2] = b.x; thVn[3] = b.y;
                } else {
                    #pragma unroll
                    for (int k = 0; k < 4; ++k) {
                        double u = (double)u_v[(size_t)(t + 1) * 1024 + 4 * t4 + k];
                        thVn[k] = log(u) - log1p(-u) - (double)bv[4 * t4 + k];
                    }
                }
            }
            { double* dot = doth; const char* Mb = wjb; apply_ph(dot, sg, np, Mb); }

            if (t + 1 < NSTEPS) {
                #pragma unroll
                for (int k = 0; k < 4; ++k) { thH[k] = thHn[k]; thV[k] = thVn[k]; }
            }

            // ---- sample free energy: fe = sv.bv + sh.(bh + doth) ----
            if (t >= NSTEPS - KLS) {
                double c = 0.0;
                #pragma unroll
                for (int k = 0; k < 4; ++k) {
                    double bvk = (double)bv[4 * t4 + k], bhk = (double)bh[4 * t4 + k];
                    c += (nv[k] ? bvk : 0.0) + (nh[k] ? (bhk + doth[k]) : 0.0);
                }
                #pragma unroll
                for (int o = 32; o > 0; o >>= 1) c += __shfl_down(c, o);
                if (lane == 0) sg.redd[wv] = c;
                __syncthreads();
                if (tid == 0)
                    fe_acc += sg.redd[0] + sg.redd[1] + sg.redd[2] + sg.redd[3];
                __syncthreads();
            }
        }
        if (tid == 0) fes[0] = fe_acc;
        return;
    }

    // ======================= GEMM1 (+ zeta + log-posterior) =======================
    const int gid = blockIdx.x - 1;
    const int n0 = (gid & 15) * 128;
    const int m0 = (gid >> 4) * 128;
    const int tx = tid & 15, ty = tid >> 4;
    const int ar = tid >> 1, ac = (tid & 1) * 4;
    const int br = tid >> 5, bc = (tid & 31) * 4;

    float acc[8][8];
    #pragma unroll
    for (int i = 0; i < 8; ++i)
        #pragma unroll
        for (int j = 0; j < 8; ++j) acc[i][j] = 0.f;

    float4 a_reg = *reinterpret_cast<const float4*>(&A[(size_t)(m0 + ar) * KDIM + ac]);
    float4 b_reg = *reinterpret_cast<const float4*>(&B[(size_t)br * NDIM + n0 + bc]);
    for (int k0 = 0; k0 < KDIM; k0 += 8) {
        __syncthreads();
        su.m.As[ac + 0][ar] = a_reg.x; su.m.As[ac + 1][ar] = a_reg.y;
        su.m.As[ac + 2][ar] = a_reg.z; su.m.As[ac + 3][ar] = a_reg.w;
        *reinterpret_cast<float4*>(&su.m.Bs[br][bc]) = b_reg;
        __syncthreads();
        if (k0 + 8 < KDIM) {
            a_reg = *reinterpret_cast<const float4*>(&A[(size_t)(m0 + ar) * KDIM + k0 + 8 + ac]);
            b_reg = *reinterpret_cast<const float4*>(&B[(size_t)(k0 + 8 + br) * NDIM + n0 + bc]);
        }
        #pragma unroll
        for (int k = 0; k < 8; ++k) {
            float av[8], bw[8];
            const float4* ap = reinterpret_cast<const float4*>(&su.m.As[k][ty * 8]);
            const float4* bp = reinterpret_cast<const float4*>(&su.m.Bs[k][tx * 8]);
            float4 a0 = ap[0], a1 = ap[1], b0 = bp[0], b1 = bp[1];
            av[0]=a0.x; av[1]=a0.y; av[2]=a0.z; av[3]=a0.w; av[4]=a1.x; av[5]=a1.y; av[6]=a1.z; av[7]=a1.w;
            bw[0]=b0.x; bw[1]=b0.y; bw[2]=b0.z; bw[3]=b0.w; bw[4]=b1.x; bw[5]=b1.y; bw[6]=b1.z; bw[7]=b1.w;
            #pragma unroll
            for (int i = 0; i < 8; ++i)
                #pragma unroll
                for (int j = 0; j < 8; ++j)
                    acc[i][j] = fmaf(av[i], bw[j], acc[i][j]);
        }
    }

    const bool isv = (n0 < VIS);
    float lpacc[8];
    #pragma unroll
    for (int i = 0; i < 8; ++i) {
        const int row = m0 + ty * 8 + i;
        float s = 0.f;
        #pragma unroll
        for (int j = 0; j < 8; ++j) {
            const int n = n0 + tx * 8 + j;
            float l = acc[i][j] + lb[n];
            float e = eps[(size_t)row * NDIM + n];
            float z = 1.f / (1.f + expf(-(l + e) * 5.f));
            float p = 1.f / (1.f + expf(-l));
            float bb;
            if (isv) { zv[(size_t)row * VIS + n] = z; bb = bv[n]; }
            else     { zh[(size_t)row * HID + (n - VIS)] = z; bb = bh[n - VIS]; }
            s += logf(z * p + (1.f - z) * (1.f - p)) + z * bb;
        }
        lpacc[i] = s;
    }
    __syncthreads();
    #pragma unroll
    for (int i = 0; i < 8; ++i) su.m.red[(ty * 8 + i) * 17 + tx] = lpacc[i];
    __syncthreads();
    if (tid < 128) {
        float s = 0.f;
        #pragma unroll
        for (int x = 0; x < 16; ++x) s += su.m.red[tid * 17 + x];
        atomicAdd(&lp_row[m0 + tid], s);
    }
}

// ---------- GEMM2: fe quadratic term: rowsum((zeta_v @ w) * zeta_h) ----------
#define BM 128
#define BN 128
#define BK 8

__global__ __launch_bounds__(256) void gemm2_fe(
    const float* __restrict__ A, const float* __restrict__ B,
    const float* __restrict__ ZH, float* __restrict__ fe_row)
{
    __shared__ float As[BK][BM];
    __shared__ float Bs[BK][BN];
    __shared__ float red[BM * 17];
    const int tid = threadIdx.x;
    const int n0 = blockIdx.x * BN;
    const int m0 = blockIdx.y * BM;
    const int tx = tid & 15, ty = tid >> 4;
    const int ar = tid >> 1, ac = (tid & 1) * 4;
    const int br = tid >> 5, bc = (tid & 31) * 4;

    float acc[8][8];
    #pragma unroll
    for (int i = 0; i < 8; ++i)
        #pragma unroll
        for (int j = 0; j < 8; ++j) acc[i][j] = 0.f;

    for (int k0 = 0; k0 < 1024; k0 += BK) {
        float4 a = *reinterpret_cast<const float4*>(&A[(size_t)(m0 + ar) * 1024 + k0 + ac]);
        float4 b = *reinterpret_cast<const float4*>(&B[(size_t)(k0 + br) * 1024 + n0 + bc]);
        __syncthreads();
        As[ac + 0][ar] = a.x; As[ac + 1][ar] = a.y; As[ac + 2][ar] = a.z; As[ac + 3][ar] = a.w;
        *reinterpret_cast<float4*>(&Bs[br][bc]) = b;
        __syncthreads();
        #pragma unroll
        for (int k = 0; k < BK; ++k) {
            float av[8], bw[8];
            const float4* ap = reinterpret_cast<const float4*>(&As[k][ty * 8]);
            const float4* bp = reinterpret_cast<const float4*>(&Bs[k][tx * 8]);
            float4 a0 = ap[0], a1 = ap[1], b0 = bp[0], b1 = bp[1];
            av[0]=a0.x; av[1]=a0.y; av[2]=a0.z; av[3]=a0.w; av[4]=a1.x; av[5]=a1.y; av[6]=a1.z; av[7]=a1.w;
            bw[0]=b0.x; bw[1]=b0.y; bw[2]=b0.z; bw[3]=b0.w; bw[4]=b1.x; bw[5]=b1.y; bw[6]=b1.z; bw[7]=b1.w;
            #pragma unroll
            for (int i = 0; i < 8; ++i)
                #pragma unroll
                for (int j = 0; j < 8; ++j)
                    acc[i][j] = fmaf(av[i], bw[j], acc[i][j]);
        }
    }

    float feacc[8];
    #pragma unroll
    for (int i = 0; i < 8; ++i) {
        const int row = m0 + ty * 8 + i;
        float s = 0.f;
        #pragma unroll
        for (int j = 0; j < 8; ++j) {
            const int n = n0 + tx * 8 + j;
            s += acc[i][j] * ZH[(size_t)row * HID + n];
        }
        feacc[i] = s;
    }
    __syncthreads();
    #pragma unroll
    for (int i = 0; i < 8; ++i) red[(ty * 8 + i) * 17 + tx] = feacc[i];
    __syncthreads();
    if (tid < BM) {
        float s = 0.f;
        #pragma unroll
        for (int x = 0; x < 16; ++x) s += red[tid * 17 + x];
        atomicAdd(&fe_row[m0 + tid], s);
    }
}

__global__ __launch_bounds__(256) void final_kl(
    const float* __restrict__ lp_row, const float* __restrict__ fe_row,
    const double* __restrict__ fe_sum, float* __restrict__ out_kl)
{
    __shared__ double dred[256];
    const int tid = threadIdx.x;
    double acc = 0.0;
    for (int r = tid; r < NROW; r += 256)
        acc += (double)lp_row[r] + (double)fe_row[r];
    dred[tid] = acc;
    __syncthreads();
    for (int off = 128; off > 0; off >>= 1) {
        if (tid < off) dred[tid] += dred[tid + off];
        __syncthreads();
    }
    if (tid == 0) out_kl[0] = (float)(dred[0] / 8192.0 - fe_sum[0] / 10.0);
}

extern "C" void kernel_launch(void* const* d_in, const int* in_sizes, int n_in,
                              void* d_out, int out_size, void* d_ws, size_t ws_size,
                              hipStream_t stream)
{
    const float* vecs   = (const float*)d_in[0];
    const float* lw     = (const float*)d_in[1];
    const float* lb     = (const float*)d_in[2];
    const float* w      = (const float*)d_in[3];
    const float* bv     = (const float*)d_in[4];
    const float* bh     = (const float*)d_in[5];
    const float* eps    = (const float*)d_in[6];
    const float* u_init = (const float*)d_in[7];
    const float* u_h    = (const float*)d_in[8];
    const float* u_v    = (const float*)d_in[9];

    float* out    = (float*)d_out;
    float* zv     = out;
    float* zh     = out + (size_t)NROW * VIS;
    float* out_kl = out + (size_t)NROW * 2048;

    const size_t thr_sz = (size_t)NSTEPS * 1024 * 8;      // 16.47 MB each
    const size_t pre_need = (4u << 20) + 2 * thr_sz + 65536 + 64;
    const int use_pre = (ws_size >= pre_need) ? 1 : 0;

    char* ws = (char*)d_ws;
    float*  wT   = (float*)ws;                            // 4 MB
    double* thrH = use_pre ? (double*)(ws + (4u << 20)) : nullptr;
    double* thrV = use_pre ? (double*)(ws + (4u << 20) + thr_sz) : nullptr;
    size_t tail  = (4u << 20) + (use_pre ? 2 * thr_sz : 0);
    float*  lp_row = (float*)(ws + tail);                 // 8192 f32
    float*  fe_row = lp_row + 8192;                       // 8192 f32
    double* fes    = (double*)(ws + tail + 65536);

    init_zero<<<64, 256, 0, stream>>>(lp_row, 16384);     // lp_row + fe_row
    transpose_w_k<<<dim3(32, 32), 256, 0, stream>>>(w, wT);
    if (use_pre)
        prep_thr<<<(NSTEPS * 1024 + 255) / 256, 256, 0, stream>>>(u_h, u_v, bh, bv, thrH, thrV);
    fused_k<<<1 + 1024, 256, 0, stream>>>(
        w, wT, bv, bh, u_init, u_h, u_v, fes, thrH, thrV, use_pre,
        vecs, lw, lb, eps, zv, zh, lp_row);
    gemm2_fe<<<dim3(8, 64), 256, 0, stream>>>(zv, w, zh, fe_row);
    final_kl<<<1, 256, 0, stream>>>(lp_row, fe_row, fes, out_kl);
}